// Round 11
// baseline (430.397 us; speedup 1.0000x reference)
//
#include <hip/hip_runtime.h>
#include <cmath>
#include <cstdint>

constexpr int T_STEPS = 512;
constexpr int BATCH   = 1024;
constexpr int DIM     = 128;
constexpr int LATENT  = 256;
constexpr int OUT_DIM = 64;
constexpr int ROWS    = 16;
constexpr int TCHUNK  = 64;     // phase-1 time steps per block (grid.y = 8)

typedef __attribute__((ext_vector_type(8))) short bf16x8;
typedef __attribute__((ext_vector_type(4))) float f32x4;
typedef __attribute__((ext_vector_type(4))) int   i32x4;

__device__ __forceinline__ uint32_t f2bf(float f) {
    uint32_t u = __builtin_bit_cast(uint32_t, f);
    return (u + 0x7FFFu + ((u >> 16) & 1u)) >> 16;
}
__device__ __forceinline__ float bf2f(uint32_t b) {
    return __builtin_bit_cast(float, b << 16);
}
__device__ __forceinline__ uint32_t pk2(float a, float b) {
    return f2bf(a) | (f2bf(b) << 16);
}
__device__ __forceinline__ float fast_tanh(float v) {
    float e = __builtin_amdgcn_exp2f(v * 2.885390081777927f);   // e^{2v}
    return __builtin_fmaf(-2.0f, __builtin_amdgcn_rcpf(e + 1.0f), 1.0f);
}
__device__ __forceinline__ float fast_sigmoid(float v) {
    float e = __builtin_amdgcn_exp2f(v * -1.4426950408889634f); // e^{-v}
    return __builtin_amdgcn_rcpf(e + 1.0f);
}
__device__ __forceinline__ int q8(float v, float inv) {
    return (int)__builtin_rintf(v * inv);
}
__device__ __forceinline__ uint32_t pack4(int a, int b, int c, int d) {
    return (uint32_t)(a & 255) | ((uint32_t)(b & 255) << 8) |
           ((uint32_t)(c & 255) << 16) | ((uint32_t)(d & 255) << 24);
}
__device__ __forceinline__ int swz(int sl, int b) {
    return (sl ^ (b & 3) ^ ((b >> 2) & 3)) & 3;
}

// ---- shared macros (fragment conventions verified in rounds 5-10) ----
#define WHQ(J) q8(_p[(size_t)(J) * LATENT], _inv)
#define LOADWH(NAME, WC, S, INV)                                            \
    i32x4 NAME; {                                                           \
        const float* _p = Wh + (size_t)((S) * 64 + kgrp * 16) * LATENT + (WC); \
        const float _inv = (INV);                                           \
        NAME[0] = (int)pack4(WHQ(0),  WHQ(1),  WHQ(2),  WHQ(3));            \
        NAME[1] = (int)pack4(WHQ(4),  WHQ(5),  WHQ(6),  WHQ(7));            \
        NAME[2] = (int)pack4(WHQ(8),  WHQ(9),  WHQ(10), WHQ(11));           \
        NAME[3] = (int)pack4(WHQ(12), WHQ(13), WHQ(14), WHQ(15));           \
    }
#define LOADWX(NAME, WC, S)                                                 \
    bf16x8 NAME; {                                                          \
        const float* _p = Wi + (size_t)((S) * 32 + kgrp * 8) * LATENT + (WC); \
        NAME[0] = (short)f2bf(_p[0]);                                       \
        NAME[1] = (short)f2bf(_p[(size_t)1 * LATENT]);                      \
        NAME[2] = (short)f2bf(_p[(size_t)2 * LATENT]);                      \
        NAME[3] = (short)f2bf(_p[(size_t)3 * LATENT]);                      \
        NAME[4] = (short)f2bf(_p[(size_t)4 * LATENT]);                      \
        NAME[5] = (short)f2bf(_p[(size_t)5 * LATENT]);                      \
        NAME[6] = (short)f2bf(_p[(size_t)6 * LATENT]);                      \
        NAME[7] = (short)f2bf(_p[(size_t)7 * LATENT]);                      \
    }

// =====================  PHASE 1: xi = x @ Wi + bi  =====================
// grid = (64 batch-blocks, 8 t-chunks) x 512 thr = 8 waves; wave wv owns
// latent tiles tg=2wv,2wv+1. Output written PRE-SWIZZLED into phase-2's
// per-lane layout: uint2 slot = ((t*64+blk)<<10) + (wv<<7) + tile*64 + lane,
// holding xi[b0+ (lane&15)][tg*16 + (lane>>4)*4 + 0..3] as 4 bf16.
__global__ __launch_bounds__(512)
void rnn_xi_gemm(const float* __restrict__ x,    // [512][1024][128]
                 const float* __restrict__ Wi,   // [128][256]
                 const float* __restrict__ bi,   // [256]
                 uint2* __restrict__ xi)
{
    __shared__ __align__(16) uint8_t xls[2][4096];   // x^T bf16 [4][16][64B]

    const int tid  = threadIdx.x;
    const int lane = tid & 63;
    const int wv   = tid >> 6;
    const int blk  = blockIdx.x;
    const int t0   = blockIdx.y * TCHUNK;
    const int b0   = blk * ROWS;
    const int b15  = lane & 15;
    const int kgrp = lane >> 4;
    const int tg0  = wv * 2, tg1 = wv * 2 + 1;
    const int wcol0 = tg0 * 16 + b15;
    const int wcol1 = wcol0 + 16;

    LOADWX(AX0_0, wcol0, 0) LOADWX(AX0_1, wcol0, 1)
    LOADWX(AX0_2, wcol0, 2) LOADWX(AX0_3, wcol0, 3)
    LOADWX(AX1_0, wcol1, 0) LOADWX(AX1_1, wcol1, 1)
    LOADWX(AX1_2, wcol1, 2) LOADWX(AX1_3, wcol1, 3)

    const float cb0_0 = bi[tg0 * 16 + kgrp * 4 + 0];
    const float cb0_1 = bi[tg0 * 16 + kgrp * 4 + 1];
    const float cb0_2 = bi[tg0 * 16 + kgrp * 4 + 2];
    const float cb0_3 = bi[tg0 * 16 + kgrp * 4 + 3];
    const float cb1_0 = bi[tg1 * 16 + kgrp * 4 + 0];
    const float cb1_1 = bi[tg1 * 16 + kgrp * 4 + 1];
    const float cb1_2 = bi[tg1 * 16 + kgrp * 4 + 2];
    const float cb1_3 = bi[tg1 * 16 + kgrp * 4 + 3];

    const int pr = tid & 15;
    const int pq = tid >> 4;                // 0..31
    const int stb = (pq >> 3) * 1024 + pr * 64 +
                    (swz((pq >> 1) & 3, pr) << 4) + (pq & 1) * 8;
    {
        const float* xq = x + ((size_t)t0 * BATCH + b0 + pr) * DIM + pq * 4;
        float4 xv = *reinterpret_cast<const float4*>(xq);
        *reinterpret_cast<uint2*>(&xls[0][stb]) =
            make_uint2(pk2(xv.x, xv.y), pk2(xv.z, xv.w));
    }
    __syncthreads();

    const int hrd = b15 * 64 + (swz(kgrp, b15) << 4);
    const float* xp = x + ((size_t)(t0 + 1) * BATCH + b0 + pr) * DIM + pq * 4;
    uint2* wp = xi + ((((size_t)t0 * 64 + blk) << 10) + (wv << 7) + lane);

    int cur = 0;
    for (int tt = 0; tt < TCHUNK; ++tt) {
        const bool pf = (tt + 1 < TCHUNK);
        float4 xv;
        if (pf) {
            xv = *reinterpret_cast<const float4*>(xp);
            xp += (size_t)BATCH * DIM;
        }

        const uint8_t* xb = &xls[cur][hrd];
        bf16x8 bx0 = *reinterpret_cast<const bf16x8*>(xb);
        bf16x8 bx1 = *reinterpret_cast<const bf16x8*>(xb + 1024);
        bf16x8 bx2 = *reinterpret_cast<const bf16x8*>(xb + 2048);
        bf16x8 bx3 = *reinterpret_cast<const bf16x8*>(xb + 3072);

        f32x4 c0 = {cb0_0, cb0_1, cb0_2, cb0_3};
        f32x4 c1 = {cb1_0, cb1_1, cb1_2, cb1_3};
        c0 = __builtin_amdgcn_mfma_f32_16x16x32_bf16(AX0_0, bx0, c0, 0, 0, 0);
        c1 = __builtin_amdgcn_mfma_f32_16x16x32_bf16(AX1_0, bx0, c1, 0, 0, 0);
        c0 = __builtin_amdgcn_mfma_f32_16x16x32_bf16(AX0_1, bx1, c0, 0, 0, 0);
        c1 = __builtin_amdgcn_mfma_f32_16x16x32_bf16(AX1_1, bx1, c1, 0, 0, 0);
        c0 = __builtin_amdgcn_mfma_f32_16x16x32_bf16(AX0_2, bx2, c0, 0, 0, 0);
        c1 = __builtin_amdgcn_mfma_f32_16x16x32_bf16(AX1_2, bx2, c1, 0, 0, 0);
        c0 = __builtin_amdgcn_mfma_f32_16x16x32_bf16(AX0_3, bx3, c0, 0, 0, 0);
        c1 = __builtin_amdgcn_mfma_f32_16x16x32_bf16(AX1_3, bx3, c1, 0, 0, 0);

        wp[0]  = make_uint2(pk2(c0[0], c0[1]), pk2(c0[2], c0[3]));
        wp[64] = make_uint2(pk2(c1[0], c1[1]), pk2(c1[2], c1[3]));
        wp += 65536;     // 64 blocks * 1024 slots per t

        if (pf)
            *reinterpret_cast<uint2*>(&xls[cur ^ 1][stb]) =
                make_uint2(pk2(xv.x, xv.y), pk2(xv.z, xv.w));
        __syncthreads();
        cur ^= 1;
    }
}

// =====================  PHASE 2: the recurrence  =====================
// r10's kernel minus the whole x-part: per step/wave 4 h b128 reads + 8 i8
// MFMAs + 2 prefetched xi uint2 loads; LDS 32KB/step (r10: 64KB).
__global__ __launch_bounds__(512)
void rnn_rec(const float* __restrict__ h0,   // [1024][256]
             const float* __restrict__ Wh,   // [256][256]
             const float* __restrict__ Wd,   // [256][64]
             const float* __restrict__ bd,   // [64]
             const uint2* __restrict__ xi,   // phase-1 layout
             float* __restrict__ out)        // [1024][64]
{
    __shared__ __align__(16) uint8_t hls[2][4096];   // h^T i8 [4][16][64B]

    const int tid  = threadIdx.x;
    const int lane = tid & 63;
    const int wv   = tid >> 6;
    const int blk  = blockIdx.x;
    const int b0   = blk * ROWS;
    const int b15  = lane & 15;
    const int kgrp = lane >> 4;
    const int tg0  = wv * 2, tg1 = wv * 2 + 1;
    const int wcol0 = tg0 * 16 + b15;
    const int wcol1 = wcol0 + 16;

    // per-column max of |Wh| for i8 scale
    float cmh0 = 0.f, cmh1 = 0.f;
    {
        const float* p0 = Wh + (size_t)(kgrp * 16) * LATENT + wcol0;
        #pragma unroll 4
        for (int i = 0; i < 64; ++i) {
            const size_t off = (size_t)((i >> 4) * 64 + (i & 15)) * LATENT;
            cmh0 = fmaxf(cmh0, fabsf(p0[off]));
            cmh1 = fmaxf(cmh1, fabsf(p0[off + 16]));
        }
        cmh0 = fmaxf(cmh0, __shfl_xor(cmh0, 16));
        cmh0 = fmaxf(cmh0, __shfl_xor(cmh0, 32));
        cmh1 = fmaxf(cmh1, __shfl_xor(cmh1, 16));
        cmh1 = fmaxf(cmh1, __shfl_xor(cmh1, 32));
    }
    const float ih0 = cmh0 > 0.f ? 127.f / cmh0 : 0.f;
    const float ih1 = cmh1 > 0.f ? 127.f / cmh1 : 0.f;

    LOADWH(AH0_0, wcol0, 0, ih0) LOADWH(AH0_1, wcol0, 1, ih0)
    LOADWH(AH0_2, wcol0, 2, ih0) LOADWH(AH0_3, wcol0, 3, ih0)
    LOADWH(AH1_0, wcol1, 0, ih1) LOADWH(AH1_1, wcol1, 1, ih1)
    LOADWH(AH1_2, wcol1, 2, ih1) LOADWH(AH1_3, wcol1, 3, ih1)

    const float dh0_0 = __shfl(cmh0, kgrp * 4 + 0) * (1.f / 16129.f);
    const float dh0_1 = __shfl(cmh0, kgrp * 4 + 1) * (1.f / 16129.f);
    const float dh0_2 = __shfl(cmh0, kgrp * 4 + 2) * (1.f / 16129.f);
    const float dh0_3 = __shfl(cmh0, kgrp * 4 + 3) * (1.f / 16129.f);
    const float dh1_0 = __shfl(cmh1, kgrp * 4 + 0) * (1.f / 16129.f);
    const float dh1_1 = __shfl(cmh1, kgrp * 4 + 1) * (1.f / 16129.f);
    const float dh1_2 = __shfl(cmh1, kgrp * 4 + 2) * (1.f / 16129.f);
    const float dh1_3 = __shfl(cmh1, kgrp * 4 + 3) * (1.f / 16129.f);

    // stage h0 as i8
    const int pr = tid & 15;
    const int pq = tid >> 4;
    const int stb = (pq >> 3) * 1024 + pr * 64 +
                    (swz((pq >> 1) & 3, pr) << 4) + (pq & 1) * 8;
    {
        const float* hp = h0 + (size_t)(b0 + pr) * LATENT + pq * 8;
        uint32_t u0 = pack4(q8(hp[0], 127.f), q8(hp[1], 127.f),
                            q8(hp[2], 127.f), q8(hp[3], 127.f));
        uint32_t u1 = pack4(q8(hp[4], 127.f), q8(hp[5], 127.f),
                            q8(hp[6], 127.f), q8(hp[7], 127.f));
        *reinterpret_cast<uint2*>(&hls[0][stb]) = make_uint2(u0, u1);
    }
    __syncthreads();

    const int hrd = b15 * 64 + (swz(kgrp, b15) << 4);
    const int wb0 = (tg0 >> 2) * 1024 + b15 * 64 +
                    (swz(tg0 & 3, b15) << 4) + kgrp * 4;
    const int wb1 = (tg1 >> 2) * 1024 + b15 * 64 +
                    (swz(tg1 & 3, b15) << 4) + kgrp * 4;

    const uint2* xr = xi + ((size_t)blk << 10) + (wv << 7) + lane;
    uint2 xa0 = xr[0];
    uint2 xa1 = xr[64];

    int cur = 0;
    for (int t = 0; t < T_STEPS; ++t) {
        const bool pf = (t + 1 < T_STEPS);
        uint2 xb0, xb1;
        if (pf) {               // prefetch next step's xi
            xb0 = xr[65536];
            xb1 = xr[65536 + 64];
        }

        const uint8_t* hb = &hls[cur][hrd];
        i32x4 bh0 = *reinterpret_cast<const i32x4*>(hb);
        i32x4 bh1 = *reinterpret_cast<const i32x4*>(hb + 1024);
        i32x4 bh2 = *reinterpret_cast<const i32x4*>(hb + 2048);
        i32x4 bh3 = *reinterpret_cast<const i32x4*>(hb + 3072);

        i32x4 ch0 = {0, 0, 0, 0}, ch1 = {0, 0, 0, 0};
        ch0 = __builtin_amdgcn_mfma_i32_16x16x64_i8(AH0_0, bh0, ch0, 0, 0, 0);
        ch1 = __builtin_amdgcn_mfma_i32_16x16x64_i8(AH1_0, bh0, ch1, 0, 0, 0);
        ch0 = __builtin_amdgcn_mfma_i32_16x16x64_i8(AH0_1, bh1, ch0, 0, 0, 0);
        ch1 = __builtin_amdgcn_mfma_i32_16x16x64_i8(AH1_1, bh1, ch1, 0, 0, 0);
        ch0 = __builtin_amdgcn_mfma_i32_16x16x64_i8(AH0_2, bh2, ch0, 0, 0, 0);
        ch1 = __builtin_amdgcn_mfma_i32_16x16x64_i8(AH1_2, bh2, ch1, 0, 0, 0);
        ch0 = __builtin_amdgcn_mfma_i32_16x16x64_i8(AH0_3, bh3, ch0, 0, 0, 0);
        ch1 = __builtin_amdgcn_mfma_i32_16x16x64_i8(AH1_3, bh3, ch1, 0, 0, 0);

        const int nxt = cur ^ 1;
        {   // tile0: h' = tanh(dequant(ch) + xi)
            float v0 = fast_tanh(__builtin_fmaf((float)ch0[0], dh0_0, bf2f(xa0.x & 0xFFFFu)));
            float v1 = fast_tanh(__builtin_fmaf((float)ch0[1], dh0_1, bf2f(xa0.x >> 16)));
            float v2 = fast_tanh(__builtin_fmaf((float)ch0[2], dh0_2, bf2f(xa0.y & 0xFFFFu)));
            float v3 = fast_tanh(__builtin_fmaf((float)ch0[3], dh0_3, bf2f(xa0.y >> 16)));
            *reinterpret_cast<uint32_t*>(&hls[nxt][wb0]) =
                pack4(q8(v0, 127.f), q8(v1, 127.f), q8(v2, 127.f), q8(v3, 127.f));
        }
        {   // tile1
            float v0 = fast_tanh(__builtin_fmaf((float)ch1[0], dh1_0, bf2f(xa1.x & 0xFFFFu)));
            float v1 = fast_tanh(__builtin_fmaf((float)ch1[1], dh1_1, bf2f(xa1.x >> 16)));
            float v2 = fast_tanh(__builtin_fmaf((float)ch1[2], dh1_2, bf2f(xa1.y & 0xFFFFu)));
            float v3 = fast_tanh(__builtin_fmaf((float)ch1[3], dh1_3, bf2f(xa1.y >> 16)));
            *reinterpret_cast<uint32_t*>(&hls[nxt][wb1]) =
                pack4(q8(v0, 127.f), q8(v1, 127.f), q8(v2, 127.f), q8(v3, 127.f));
        }

        if (pf) { xa0 = xb0; xa1 = xb1; }
        xr += 65536;
        __syncthreads();
        cur = nxt;
    }

    // decode: out = sigmoid(h/127 @ Wd + bd), 2 rows per thread
    {
        const int o  = tid & 63;
        const int rb = tid >> 6;
        float s0 = 0.f, s1 = 0.f;
        #pragma unroll 4
        for (int k = 0; k < LATENT; k += 4) {
            const int sl   = (k >> 4) & 3;
            const int base = (k >> 6) * 1024 + (k & 15);
            const uint32_t pA = *reinterpret_cast<const uint32_t*>(
                &hls[cur][base + rb * 64 + (swz(sl, rb) << 4)]);
            const uint32_t pB = *reinterpret_cast<const uint32_t*>(
                &hls[cur][base + (rb + 8) * 64 + (swz(sl, rb + 8) << 4)]);
            const float w0 = Wd[(size_t)(k + 0) * OUT_DIM + o];
            const float w1 = Wd[(size_t)(k + 1) * OUT_DIM + o];
            const float w2 = Wd[(size_t)(k + 2) * OUT_DIM + o];
            const float w3 = Wd[(size_t)(k + 3) * OUT_DIM + o];
            s0 += (float)(int8_t)(pA) * w0 + (float)(int8_t)(pA >> 8) * w1
                + (float)(int8_t)(pA >> 16) * w2 + (float)(int8_t)(pA >> 24) * w3;
            s1 += (float)(int8_t)(pB) * w0 + (float)(int8_t)(pB >> 8) * w1
                + (float)(int8_t)(pB >> 16) * w2 + (float)(int8_t)(pB >> 24) * w3;
        }
        out[(size_t)(b0 + rb) * OUT_DIM + o] =
            fast_sigmoid(bd[o] + s0 * (1.f / 127.f));
        out[(size_t)(b0 + rb + 8) * OUT_DIM + o] =
            fast_sigmoid(bd[o] + s1 * (1.f / 127.f));
    }
}

// =====================  FALLBACK: round-10 fused kernel  =====================
__global__ __launch_bounds__(512)
void rnn_i8h(const float* __restrict__ x, const float* __restrict__ h0,
             const float* __restrict__ Wi, const float* __restrict__ bi,
             const float* __restrict__ Wh, const float* __restrict__ Wd,
             const float* __restrict__ bd, float* __restrict__ out)
{
    __shared__ __align__(16) uint8_t hls[2][4096];
    __shared__ __align__(16) uint8_t xls[2][4096];

    const int tid  = threadIdx.x;
    const int lane = tid & 63;
    const int wv   = tid >> 6;
    const int b0   = blockIdx.x * ROWS;
    const int b15  = lane & 15;
    const int kgrp = lane >> 4;
    const int tg0  = wv * 2, tg1 = wv * 2 + 1;
    const int wcol0 = tg0 * 16 + b15;
    const int wcol1 = wcol0 + 16;

    float cmh0 = 0.f, cmh1 = 0.f;
    {
        const float* p0 = Wh + (size_t)(kgrp * 16) * LATENT + wcol0;
        #pragma unroll 4
        for (int i = 0; i < 64; ++i) {
            const size_t off = (size_t)((i >> 4) * 64 + (i & 15)) * LATENT;
            cmh0 = fmaxf(cmh0, fabsf(p0[off]));
            cmh1 = fmaxf(cmh1, fabsf(p0[off + 16]));
        }
        cmh0 = fmaxf(cmh0, __shfl_xor(cmh0, 16));
        cmh0 = fmaxf(cmh0, __shfl_xor(cmh0, 32));
        cmh1 = fmaxf(cmh1, __shfl_xor(cmh1, 16));
        cmh1 = fmaxf(cmh1, __shfl_xor(cmh1, 32));
    }
    const float ih0 = cmh0 > 0.f ? 127.f / cmh0 : 0.f;
    const float ih1 = cmh1 > 0.f ? 127.f / cmh1 : 0.f;

    LOADWH(FH0_0, wcol0, 0, ih0) LOADWH(FH0_1, wcol0, 1, ih0)
    LOADWH(FH0_2, wcol0, 2, ih0) LOADWH(FH0_3, wcol0, 3, ih0)
    LOADWH(FH1_0, wcol1, 0, ih1) LOADWH(FH1_1, wcol1, 1, ih1)
    LOADWH(FH1_2, wcol1, 2, ih1) LOADWH(FH1_3, wcol1, 3, ih1)
    LOADWX(FX0_0, wcol0, 0) LOADWX(FX0_1, wcol0, 1)
    LOADWX(FX0_2, wcol0, 2) LOADWX(FX0_3, wcol0, 3)
    LOADWX(FX1_0, wcol1, 0) LOADWX(FX1_1, wcol1, 1)
    LOADWX(FX1_2, wcol1, 2) LOADWX(FX1_3, wcol1, 3)

    const float dh0_0 = __shfl(cmh0, kgrp * 4 + 0) * (1.f / 16129.f);
    const float dh0_1 = __shfl(cmh0, kgrp * 4 + 1) * (1.f / 16129.f);
    const float dh0_2 = __shfl(cmh0, kgrp * 4 + 2) * (1.f / 16129.f);
    const float dh0_3 = __shfl(cmh0, kgrp * 4 + 3) * (1.f / 16129.f);
    const float dh1_0 = __shfl(cmh1, kgrp * 4 + 0) * (1.f / 16129.f);
    const float dh1_1 = __shfl(cmh1, kgrp * 4 + 1) * (1.f / 16129.f);
    const float dh1_2 = __shfl(cmh1, kgrp * 4 + 2) * (1.f / 16129.f);
    const float dh1_3 = __shfl(cmh1, kgrp * 4 + 3) * (1.f / 16129.f);
    const float cb0_0 = bi[tg0 * 16 + kgrp * 4 + 0];
    const float cb0_1 = bi[tg0 * 16 + kgrp * 4 + 1];
    const float cb0_2 = bi[tg0 * 16 + kgrp * 4 + 2];
    const float cb0_3 = bi[tg0 * 16 + kgrp * 4 + 3];
    const float cb1_0 = bi[tg1 * 16 + kgrp * 4 + 0];
    const float cb1_1 = bi[tg1 * 16 + kgrp * 4 + 1];
    const float cb1_2 = bi[tg1 * 16 + kgrp * 4 + 2];
    const float cb1_3 = bi[tg1 * 16 + kgrp * 4 + 3];

    const int pr = tid & 15;
    const int pq = tid >> 4;
    const int stb = (pq >> 3) * 1024 + pr * 64 +
                    (swz((pq >> 1) & 3, pr) << 4) + (pq & 1) * 8;
    {
        const float* hp = h0 + (size_t)(b0 + pr) * LATENT + pq * 8;
        uint32_t u0 = pack4(q8(hp[0], 127.f), q8(hp[1], 127.f),
                            q8(hp[2], 127.f), q8(hp[3], 127.f));
        uint32_t u1 = pack4(q8(hp[4], 127.f), q8(hp[5], 127.f),
                            q8(hp[6], 127.f), q8(hp[7], 127.f));
        *reinterpret_cast<uint2*>(&hls[0][stb]) = make_uint2(u0, u1);
        const float* xq = x + (size_t)(b0 + pr) * DIM + pq * 4;
        float4 xv = *reinterpret_cast<const float4*>(xq);
        *reinterpret_cast<uint2*>(&xls[0][stb]) =
            make_uint2(pk2(xv.x, xv.y), pk2(xv.z, xv.w));
    }
    __syncthreads();

    const int hrd = b15 * 64 + (swz(kgrp, b15) << 4);
    const int wb0 = (tg0 >> 2) * 1024 + b15 * 64 +
                    (swz(tg0 & 3, b15) << 4) + kgrp * 4;
    const int wb1 = (tg1 >> 2) * 1024 + b15 * 64 +
                    (swz(tg1 & 3, b15) << 4) + kgrp * 4;
    const float* xp = x + ((size_t)BATCH + b0 + pr) * DIM + pq * 4;

    int cur = 0;
    for (int t = 0; t < T_STEPS; ++t) {
        const bool pf = (t + 1 < T_STEPS);
        float4 xv;
        if (pf) {
            xv = *reinterpret_cast<const float4*>(xp);
            xp += (size_t)BATCH * DIM;
        }
        const uint8_t* hb = &hls[cur][hrd];
        const uint8_t* xb = &xls[cur][hrd];
        i32x4  bh0 = *reinterpret_cast<const i32x4*>(hb);
        i32x4  bh1 = *reinterpret_cast<const i32x4*>(hb + 1024);
        i32x4  bh2 = *reinterpret_cast<const i32x4*>(hb + 2048);
        i32x4  bh3 = *reinterpret_cast<const i32x4*>(hb + 3072);
        bf16x8 bx0 = *reinterpret_cast<const bf16x8*>(xb);
        bf16x8 bx1 = *reinterpret_cast<const bf16x8*>(xb + 1024);
        bf16x8 bx2 = *reinterpret_cast<const bf16x8*>(xb + 2048);
        bf16x8 bx3 = *reinterpret_cast<const bf16x8*>(xb + 3072);

        i32x4 ch0 = {0, 0, 0, 0}, ch1 = {0, 0, 0, 0};
        f32x4 cx0 = {cb0_0, cb0_1, cb0_2, cb0_3};
        f32x4 cx1 = {cb1_0, cb1_1, cb1_2, cb1_3};
        ch0 = __builtin_amdgcn_mfma_i32_16x16x64_i8(FH0_0, bh0, ch0, 0, 0, 0);
        ch1 = __builtin_amdgcn_mfma_i32_16x16x64_i8(FH1_0, bh0, ch1, 0, 0, 0);
        cx0 = __builtin_amdgcn_mfma_f32_16x16x32_bf16(FX0_0, bx0, cx0, 0, 0, 0);
        cx1 = __builtin_amdgcn_mfma_f32_16x16x32_bf16(FX1_0, bx0, cx1, 0, 0, 0);
        ch0 = __builtin_amdgcn_mfma_i32_16x16x64_i8(FH0_1, bh1, ch0, 0, 0, 0);
        ch1 = __builtin_amdgcn_mfma_i32_16x16x64_i8(FH1_1, bh1, ch1, 0, 0, 0);
        cx0 = __builtin_amdgcn_mfma_f32_16x16x32_bf16(FX0_1, bx1, cx0, 0, 0, 0);
        cx1 = __builtin_amdgcn_mfma_f32_16x16x32_bf16(FX1_1, bx1, cx1, 0, 0, 0);
        ch0 = __builtin_amdgcn_mfma_i32_16x16x64_i8(FH0_2, bh2, ch0, 0, 0, 0);
        ch1 = __builtin_amdgcn_mfma_i32_16x16x64_i8(FH1_2, bh2, ch1, 0, 0, 0);
        cx0 = __builtin_amdgcn_mfma_f32_16x16x32_bf16(FX0_2, bx2, cx0, 0, 0, 0);
        cx1 = __builtin_amdgcn_mfma_f32_16x16x32_bf16(FX1_2, bx2, cx1, 0, 0, 0);
        ch0 = __builtin_amdgcn_mfma_i32_16x16x64_i8(FH0_3, bh3, ch0, 0, 0, 0);
        ch1 = __builtin_amdgcn_mfma_i32_16x16x64_i8(FH1_3, bh3, ch1, 0, 0, 0);
        cx0 = __builtin_amdgcn_mfma_f32_16x16x32_bf16(FX0_3, bx3, cx0, 0, 0, 0);
        cx1 = __builtin_amdgcn_mfma_f32_16x16x32_bf16(FX1_3, bx3, cx1, 0, 0, 0);

        const int nxt = cur ^ 1;
        {
            float v0 = fast_tanh(__builtin_fmaf((float)ch0[0], dh0_0, cx0[0]));
            float v1 = fast_tanh(__builtin_fmaf((float)ch0[1], dh0_1, cx0[1]));
            float v2 = fast_tanh(__builtin_fmaf((float)ch0[2], dh0_2, cx0[2]));
            float v3 = fast_tanh(__builtin_fmaf((float)ch0[3], dh0_3, cx0[3]));
            *reinterpret_cast<uint32_t*>(&hls[nxt][wb0]) =
                pack4(q8(v0, 127.f), q8(v1, 127.f), q8(v2, 127.f), q8(v3, 127.f));
        }
        {
            float v0 = fast_tanh(__builtin_fmaf((float)ch1[0], dh1_0, cx1[0]));
            float v1 = fast_tanh(__builtin_fmaf((float)ch1[1], dh1_1, cx1[1]));
            float v2 = fast_tanh(__builtin_fmaf((float)ch1[2], dh1_2, cx1[2]));
            float v3 = fast_tanh(__builtin_fmaf((float)ch1[3], dh1_3, cx1[3]));
            *reinterpret_cast<uint32_t*>(&hls[nxt][wb1]) =
                pack4(q8(v0, 127.f), q8(v1, 127.f), q8(v2, 127.f), q8(v3, 127.f));
        }
        if (pf)
            *reinterpret_cast<uint2*>(&xls[nxt][stb]) =
                make_uint2(pk2(xv.x, xv.y), pk2(xv.z, xv.w));
        __syncthreads();
        cur = nxt;
    }

    {
        const int o  = tid & 63;
        const int rb = tid >> 6;
        float s0 = 0.f, s1 = 0.f;
        #pragma unroll 4
        for (int k = 0; k < LATENT; k += 4) {
            const int sl   = (k >> 4) & 3;
            const int base = (k >> 6) * 1024 + (k & 15);
            const uint32_t pA = *reinterpret_cast<const uint32_t*>(
                &hls[cur][base + rb * 64 + (swz(sl, rb) << 4)]);
            const uint32_t pB = *reinterpret_cast<const uint32_t*>(
                &hls[cur][base + (rb + 8) * 64 + (swz(sl, rb + 8) << 4)]);
            const float w0 = Wd[(size_t)(k + 0) * OUT_DIM + o];
            const float w1 = Wd[(size_t)(k + 1) * OUT_DIM + o];
            const float w2 = Wd[(size_t)(k + 2) * OUT_DIM + o];
            const float w3 = Wd[(size_t)(k + 3) * OUT_DIM + o];
            s0 += (float)(int8_t)(pA) * w0 + (float)(int8_t)(pA >> 8) * w1
                + (float)(int8_t)(pA >> 16) * w2 + (float)(int8_t)(pA >> 24) * w3;
            s1 += (float)(int8_t)(pB) * w0 + (float)(int8_t)(pB >> 8) * w1
                + (float)(int8_t)(pB >> 16) * w2 + (float)(int8_t)(pB >> 24) * w3;
        }
        out[(size_t)(b0 + rb) * OUT_DIM + o] =
            fast_sigmoid(bd[o] + s0 * (1.f / 127.f));
        out[(size_t)(b0 + rb + 8) * OUT_DIM + o] =
            fast_sigmoid(bd[o] + s1 * (1.f / 127.f));
    }
}

extern "C" void kernel_launch(void* const* d_in, const int* in_sizes, int n_in,
                              void* d_out, int out_size, void* d_ws, size_t ws_size,
                              hipStream_t stream) {
    const float* x  = (const float*)d_in[0];
    const float* h0 = (const float*)d_in[1];
    const float* Wi = (const float*)d_in[2];
    const float* bi = (const float*)d_in[3];
    const float* Wh = (const float*)d_in[4];
    const float* Wd = (const float*)d_in[5];
    const float* bd = (const float*)d_in[6];
    float* out = (float*)d_out;

    const size_t need = (size_t)T_STEPS * 64 * 1024 * sizeof(uint2); // 256 MiB
    if (ws_size >= need) {
        hipLaunchKernelGGL(rnn_xi_gemm, dim3(64, T_STEPS / TCHUNK), dim3(512),
                           0, stream, x, Wi, bi, (uint2*)d_ws);
        hipLaunchKernelGGL(rnn_rec, dim3(64), dim3(512), 0, stream,
                           h0, Wh, Wd, bd, (const uint2*)d_ws, out);
    } else {
        hipLaunchKernelGGL(rnn_i8h, dim3(BATCH / ROWS), dim3(512), 0, stream,
                           x, h0, Wi, bi, Wh, Wd, bd, out);
    }
}